// Round 4
// baseline (3076.416 us; speedup 1.0000x reference)
//
#include <hip/hip_runtime.h>

// R3: split fused layer into aggr_kernel (pure gather, max memory concurrency)
// + mlp_kernel (pure dense GEMM, in-place residual). R1/R2 showed phase-aligned
// fused blocks leave both pipes <45% busy (VALUBusy ~40%, eff mem ~2 TB/s,
// FETCH at the 8-XCD x 51MB floor). Predict: aggr ~70-120us @ occ>=80%,
// mlp ~60-90us @ VALUBusy>=65%; total ~1700-2200us.

#define N_NODES 100000
#define N_EDGES 1600000
#define HID 128
#define NUM_LAYERS 10
#define NUM_GRAPHS 64
#define SCAN_BLOCKS ((N_NODES + 255) / 256)
#define ROWS 32        // nodes per block (both kernels); N_NODES % 32 == 0
#define IDX_CAP 1024   // LDS-staged neighbor indices per 32-node block (mean 512)

// ---------------- CSR build ----------------

__global__ __launch_bounds__(256) void count_deg_kernel(const int* __restrict__ dst,
                                                        int* __restrict__ deg, int E) {
  int e = blockIdx.x * 256 + threadIdx.x;
  if (e < E) atomicAdd(&deg[dst[e]], 1);
}

__global__ __launch_bounds__(256) void block_sum_kernel(const int* __restrict__ deg,
                                                        int* __restrict__ psum, int n) {
  __shared__ int sd[256];
  int i = blockIdx.x * 256 + threadIdx.x;
  sd[threadIdx.x] = (i < n) ? deg[i] : 0;
  __syncthreads();
  for (int off = 128; off > 0; off >>= 1) {
    if (threadIdx.x < off) sd[threadIdx.x] += sd[threadIdx.x + off];
    __syncthreads();
  }
  if (threadIdx.x == 0) psum[blockIdx.x] = sd[0];
}

__global__ __launch_bounds__(512) void scan_partials_kernel(const int* __restrict__ psum,
                                                            int* __restrict__ poff, int nb) {
  __shared__ int sd[512];
  int i = threadIdx.x;
  int v = (i < nb) ? psum[i] : 0;
  sd[i] = v;
  __syncthreads();
  for (int off = 1; off < 512; off <<= 1) {
    int t = (i >= off) ? sd[i - off] : 0;
    __syncthreads();
    sd[i] += t;
    __syncthreads();
  }
  if (i < nb) poff[i] = sd[i] - v;  // exclusive
}

__global__ __launch_bounds__(256) void write_rs_kernel(const int* __restrict__ deg,
                                                       const int* __restrict__ poff,
                                                       int* __restrict__ rs,
                                                       int* __restrict__ cur, int n) {
  __shared__ int sd[256];
  int i = blockIdx.x * 256 + threadIdx.x;
  int v = (i < n) ? deg[i] : 0;
  sd[threadIdx.x] = v;
  __syncthreads();
  for (int off = 1; off < 256; off <<= 1) {
    int t = (threadIdx.x >= off) ? sd[threadIdx.x - off] : 0;
    __syncthreads();
    sd[threadIdx.x] += t;
    __syncthreads();
  }
  if (i < n) {
    int incl = poff[blockIdx.x] + sd[threadIdx.x];
    rs[i + 1] = incl;
    cur[i] = incl - v;
  }
  if (i == 0) rs[0] = 0;
}

__global__ __launch_bounds__(256) void fill_csr_kernel(const int* __restrict__ src,
                                                       const int* __restrict__ dst,
                                                       int* __restrict__ cur,
                                                       int* __restrict__ csr, int E) {
  int e = blockIdx.x * 256 + threadIdx.x;
  if (e < E) {
    int p = atomicAdd(&cur[dst[e]], 1);
    csr[p] = src[e];
  }
}

// ---------------- aggregate kernel (pure gather) ----------------
// h[v] = (1+eps)*x[v] + sum_{u->v} x[u].  32 nodes/block, 4 KB LDS, 8 blocks/CU.
// Every resident wave issues gather loads continuously -> max memory concurrency.

__global__ __launch_bounds__(256, 8) void aggr_kernel(const float* __restrict__ xin,
                                                      float* __restrict__ h,
                                                      const int* __restrict__ rs,
                                                      const int* __restrict__ csr,
                                                      const float* __restrict__ eps, int layer,
                                                      int n) {
  __shared__ int lidx[IDX_CAP];
  const int tid = threadIdx.x;
  const int row0 = blockIdx.x * ROWS;
  const float4* x4 = (const float4*)xin;
  float4* h4 = (float4*)h;
  const float s = 1.0f + eps[layer];

  int rowEnd = row0 + ROWS; if (rowEnd > n) rowEnd = n;
  const int eBase = rs[row0];
  const int cnt = rs[rowEnd] - eBase;
  const int stage = (cnt < IDX_CAP) ? cnt : IDX_CAP;
  for (int t = tid; t < stage; t += 256) lidx[t] = csr[eBase + t];
  __syncthreads();

  const int w = tid >> 5;
  const int lane = tid & 31;
#pragma unroll
  for (int it = 0; it < ROWS / 8; ++it) {
    int li = it * 8 + w;
    int node = row0 + li;
    float ax = 0.f, ay = 0.f, az = 0.f, aw = 0.f;
    if (node < n) {
      float4 v = x4[node * 32 + lane];
      ax = v.x * s; ay = v.y * s; az = v.z * s; aw = v.w * s;
      const int e0 = rs[node];
      const int m = rs[node + 1] - e0;
      const int lb = e0 - eBase;
      int i = 0;
      if (lb + m <= stage) {
        for (; i + 8 <= m; i += 8) {
          int u0 = lidx[lb + i + 0], u1 = lidx[lb + i + 1];
          int u2 = lidx[lb + i + 2], u3 = lidx[lb + i + 3];
          int u4 = lidx[lb + i + 4], u5 = lidx[lb + i + 5];
          int u6 = lidx[lb + i + 6], u7 = lidx[lb + i + 7];
          float4 t0 = x4[u0 * 32 + lane];
          float4 t1 = x4[u1 * 32 + lane];
          float4 t2 = x4[u2 * 32 + lane];
          float4 t3 = x4[u3 * 32 + lane];
          float4 t4 = x4[u4 * 32 + lane];
          float4 t5 = x4[u5 * 32 + lane];
          float4 t6 = x4[u6 * 32 + lane];
          float4 t7 = x4[u7 * 32 + lane];
          ax += t0.x + t1.x + t2.x + t3.x + t4.x + t5.x + t6.x + t7.x;
          ay += t0.y + t1.y + t2.y + t3.y + t4.y + t5.y + t6.y + t7.y;
          az += t0.z + t1.z + t2.z + t3.z + t4.z + t5.z + t6.z + t7.z;
          aw += t0.w + t1.w + t2.w + t3.w + t4.w + t5.w + t6.w + t7.w;
        }
        if (i + 4 <= m) {
          int u0 = lidx[lb + i + 0], u1 = lidx[lb + i + 1];
          int u2 = lidx[lb + i + 2], u3 = lidx[lb + i + 3];
          float4 t0 = x4[u0 * 32 + lane];
          float4 t1 = x4[u1 * 32 + lane];
          float4 t2 = x4[u2 * 32 + lane];
          float4 t3 = x4[u3 * 32 + lane];
          ax += t0.x + t1.x + t2.x + t3.x;
          ay += t0.y + t1.y + t2.y + t3.y;
          az += t0.z + t1.z + t2.z + t3.z;
          aw += t0.w + t1.w + t2.w + t3.w;
          i += 4;
        }
        if (i + 2 <= m) {
          int u0 = lidx[lb + i + 0], u1 = lidx[lb + i + 1];
          float4 t0 = x4[u0 * 32 + lane];
          float4 t1 = x4[u1 * 32 + lane];
          ax += t0.x + t1.x; ay += t0.y + t1.y;
          az += t0.z + t1.z; aw += t0.w + t1.w;
          i += 2;
        }
        if (i < m) {
          int u = lidx[lb + i];
          float4 t = x4[u * 32 + lane];
          ax += t.x; ay += t.y; az += t.z; aw += t.w;
        }
      } else {
        for (; i < m; ++i) {
          int u = csr[e0 + i];
          float4 t = x4[u * 32 + lane];
          ax += t.x; ay += t.y; az += t.z; aw += t.w;
        }
      }
      float4 r; r.x = ax; r.y = ay; r.z = az; r.w = aw;
      h4[node * 32 + lane] = r;
    }
  }
}

// ---------------- MLP kernel (pure dense) ----------------
// xout = relu( relu(h@W1+b1)@W2 + b2 [+h] ) + x.  In-place safe (xout may alias
// xres): each row's output depends only on that row's h and x.

__global__ __launch_bounds__(256, 6) void mlp_kernel(const float* __restrict__ hbuf,
                                                     const float* __restrict__ xres,
                                                     float* __restrict__ xout,
                                                     const float* __restrict__ W1,
                                                     const float* __restrict__ b1,
                                                     const float* __restrict__ W2,
                                                     const float* __restrict__ b2,
                                                     int n, int addH) {
  __shared__ float lh[ROWS * 128];
  const int tid = threadIdx.x;
  const int row0 = blockIdx.x * ROWS;
  const float4* h4 = (const float4*)hbuf;
  const float4* x4 = (const float4*)xres;
  float4* lh4 = (float4*)lh;

  // ---- Stage h tile (coalesced stream; N % ROWS == 0, no tail).
  for (int t = tid; t < ROWS * 32; t += 256) {
    lh4[t] = h4[(size_t)row0 * 32 + t];
  }
  __syncthreads();

  // ---- GEMM1 (mid = relu(h@W1+b1)); thread (rg,cg) owns rows rg*4+r, cols cg*4..
  const int cg = tid & 31;
  const int rg = tid >> 5;
  float acc[4][4];
#pragma unroll
  for (int r = 0; r < 4; ++r) { acc[r][0] = acc[r][1] = acc[r][2] = acc[r][3] = 0.f; }

  for (int k4 = 0; k4 < 32; ++k4) {
    float4 w0 = *(const float4*)(W1 + (k4 * 4 + 0) * 128 + cg * 4);
    float4 w1 = *(const float4*)(W1 + (k4 * 4 + 1) * 128 + cg * 4);
    float4 w2 = *(const float4*)(W1 + (k4 * 4 + 2) * 128 + cg * 4);
    float4 w3 = *(const float4*)(W1 + (k4 * 4 + 3) * 128 + cg * 4);
#pragma unroll
    for (int r = 0; r < 4; ++r) {
      float4 a = *(const float4*)(lh + (rg * 4 + r) * 128 + k4 * 4);
      acc[r][0] += a.x * w0.x + a.y * w1.x + a.z * w2.x + a.w * w3.x;
      acc[r][1] += a.x * w0.y + a.y * w1.y + a.z * w2.y + a.w * w3.y;
      acc[r][2] += a.x * w0.z + a.y * w1.z + a.z * w2.z + a.w * w3.z;
      acc[r][3] += a.x * w0.w + a.y * w1.w + a.z * w2.w + a.w * w3.w;
    }
  }

  // snapshot h values needed in epilogue (before lh is overwritten by mid)
  float4 hreg[4];
#pragma unroll
  for (int r = 0; r < 4; ++r) hreg[r] = *(const float4*)(lh + (rg * 4 + r) * 128 + cg * 4);
  __syncthreads();

  {
    float4 bb = *(const float4*)(b1 + cg * 4);
#pragma unroll
    for (int r = 0; r < 4; ++r) {
      float4 o;
      o.x = fmaxf(acc[r][0] + bb.x, 0.f);
      o.y = fmaxf(acc[r][1] + bb.y, 0.f);
      o.z = fmaxf(acc[r][2] + bb.z, 0.f);
      o.w = fmaxf(acc[r][3] + bb.w, 0.f);
      *(float4*)(lh + (rg * 4 + r) * 128 + cg * 4) = o;
      acc[r][0] = acc[r][1] = acc[r][2] = acc[r][3] = 0.f;
    }
  }
  __syncthreads();

  // ---- GEMM2 (out = mid@W2 + b2)
  for (int k4 = 0; k4 < 32; ++k4) {
    float4 w0 = *(const float4*)(W2 + (k4 * 4 + 0) * 128 + cg * 4);
    float4 w1 = *(const float4*)(W2 + (k4 * 4 + 1) * 128 + cg * 4);
    float4 w2 = *(const float4*)(W2 + (k4 * 4 + 2) * 128 + cg * 4);
    float4 w3 = *(const float4*)(W2 + (k4 * 4 + 3) * 128 + cg * 4);
#pragma unroll
    for (int r = 0; r < 4; ++r) {
      float4 a = *(const float4*)(lh + (rg * 4 + r) * 128 + k4 * 4);
      acc[r][0] += a.x * w0.x + a.y * w1.x + a.z * w2.x + a.w * w3.x;
      acc[r][1] += a.x * w0.y + a.y * w1.y + a.z * w2.y + a.w * w3.y;
      acc[r][2] += a.x * w0.z + a.y * w1.z + a.z * w2.z + a.w * w3.z;
      acc[r][3] += a.x * w0.w + a.y * w1.w + a.z * w2.w + a.w * w3.w;
    }
  }

  // ---- Epilogue: +b2 (+h) -> relu -> +x, write xout (in GEMM layout).
  float4 b2v = *(const float4*)(b2 + cg * 4);
  float4* xo4 = (float4*)xout;
#pragma unroll
  for (int r = 0; r < 4; ++r) {
    int row = row0 + rg * 4 + r;
    if (row < n) {
      float ox = acc[r][0] + b2v.x;
      float oy = acc[r][1] + b2v.y;
      float oz = acc[r][2] + b2v.z;
      float ow = acc[r][3] + b2v.w;
      if (addH) {
        ox += hreg[r].x; oy += hreg[r].y; oz += hreg[r].z; ow += hreg[r].w;
      }
      ox = fmaxf(ox, 0.f); oy = fmaxf(oy, 0.f); oz = fmaxf(oz, 0.f); ow = fmaxf(ow, 0.f);
      float4 xv = x4[row * 32 + cg];
      float4 o;
      o.x = ox + xv.x; o.y = oy + xv.y; o.z = oz + xv.z; o.w = ow + xv.w;
      xo4[row * 32 + cg] = o;
    }
  }
}

// ---------------- pooling (batch is sorted) ----------------

__global__ __launch_bounds__(128) void pool_kernel(const float* __restrict__ x,
                                                   const int* __restrict__ batch,
                                                   float* __restrict__ pool,
                                                   int* __restrict__ gcnt, int n) {
  const int CH = 512;
  int c = threadIdx.x;
  int n0 = blockIdx.x * CH;
  if (n0 >= n) return;
  int n1 = n0 + CH; if (n1 > n) n1 = n;
  float acc = 0.f;
  int g = batch[n0];
  int cl = 0;
  for (int i = n0; i < n1; ++i) {
    int gi = batch[i];
    if (gi != g) {
      atomicAdd(&pool[g * 128 + c], acc);
      if (c == 0) atomicAdd(&gcnt[g], cl);
      acc = 0.f; cl = 0; g = gi;
    }
    acc += x[i * 128 + c];
    cl++;
  }
  atomicAdd(&pool[g * 128 + c], acc);
  if (c == 0) atomicAdd(&gcnt[g], cl);
}

// ---------------- classifier: one block per graph ----------------

__global__ __launch_bounds__(128) void classifier_kernel(const float* __restrict__ pool,
                                                         const int* __restrict__ gcnt,
                                                         const float* __restrict__ Wc1,
                                                         const float* __restrict__ bc1,
                                                         const float* __restrict__ Wc2,
                                                         const float* __restrict__ bc2,
                                                         float* __restrict__ out) {
  __shared__ float prow[128];
  __shared__ float hid[128];
  int g = blockIdx.x;
  int c = threadIdx.x;
  float cf = (float)gcnt[g];
  if (cf < 1.f) cf = 1.f;
  prow[c] = pool[g * 128 + c] / cf;
  __syncthreads();
  float a = bc1[c];
  for (int k = 0; k < 128; ++k) a += prow[k] * Wc1[k * 128 + c];
  hid[c] = fmaxf(a, 0.f);
  __syncthreads();
  if (c < 2) {
    float a2 = bc2[c];
    for (int k = 0; k < 128; ++k) a2 += hid[k] * Wc2[k * 2 + c];
    out[g * 2 + c] = a2;
  }
}

// ---------------- launch ----------------

extern "C" void kernel_launch(void* const* d_in, const int* in_sizes, int n_in,
                              void* d_out, int out_size, void* d_ws, size_t ws_size,
                              hipStream_t stream) {
  const float* x_in = (const float*)d_in[0];
  const int* edge_index = (const int*)d_in[1];
  const int* batch = (const int*)d_in[2];
  const float* eps = (const float*)d_in[3];
  const float* W1 = (const float*)d_in[4];
  const float* b1 = (const float*)d_in[5];
  const float* W2 = (const float*)d_in[6];
  const float* b2 = (const float*)d_in[7];
  const float* Wc1 = (const float*)d_in[8];
  const float* bc1 = (const float*)d_in[9];
  const float* Wc2 = (const float*)d_in[10];
  const float* bc2 = (const float*)d_in[11];
  float* out = (float*)d_out;

  const int N = N_NODES, E = N_EDGES;
  const int* src = edge_index;
  const int* dst = edge_index + E;

  // workspace layout (same footprint as before: 2 node buffers + CSR + pool)
  float* xa = (float*)d_ws;                    // N*128 floats (layer state, updated in-place)
  float* hbuf = xa + (size_t)N * 128;          // N*128 floats (h = aggregate output)
  int* deg = (int*)(hbuf + (size_t)N * 128);   // N
  int* rs = deg + N;                           // N+1
  int* cur = rs + (N + 1);                     // N
  int* csr = cur + N;                          // E
  float* pool = (float*)(csr + E);             // 64*128
  int* gcnt = (int*)(pool + NUM_GRAPHS * 128); // 64
  int* psum = gcnt + NUM_GRAPHS;               // SCAN_BLOCKS
  int* poff = psum + SCAN_BLOCKS;              // SCAN_BLOCKS

  hipMemsetAsync(deg, 0, N * sizeof(int), stream);

  // CSR build
  count_deg_kernel<<<(E + 255) / 256, 256, 0, stream>>>(dst, deg, E);
  block_sum_kernel<<<SCAN_BLOCKS, 256, 0, stream>>>(deg, psum, N);
  scan_partials_kernel<<<1, 512, 0, stream>>>(psum, poff, SCAN_BLOCKS);
  write_rs_kernel<<<SCAN_BLOCKS, 256, 0, stream>>>(deg, poff, rs, cur, N);
  fill_csr_kernel<<<(E + 255) / 256, 256, 0, stream>>>(src, dst, cur, csr, E);

  // layers: aggr (x -> h), mlp (h, x -> x in-place; layer 0 reads input buffer)
  const int NB = (N + ROWS - 1) / ROWS;
  for (int i = 0; i < NUM_LAYERS; ++i) {
    const float* xi = (i == 0) ? x_in : xa;
    aggr_kernel<<<NB, 256, 0, stream>>>(xi, hbuf, rs, csr, eps, i, N);
    mlp_kernel<<<NB, 256, 0, stream>>>(hbuf, xi, xa,
                                       W1 + (size_t)i * 128 * 128, b1 + (size_t)i * 128,
                                       W2 + (size_t)i * 128 * 128, b2 + (size_t)i * 128,
                                       N, i > 0 ? 1 : 0);
  }

  // pooling + classifier
  hipMemsetAsync(pool, 0, NUM_GRAPHS * 128 * sizeof(float), stream);
  hipMemsetAsync(gcnt, 0, NUM_GRAPHS * sizeof(int), stream);
  pool_kernel<<<(N + 511) / 512, 128, 0, stream>>>(xa, batch, pool, gcnt, N);
  classifier_kernel<<<NUM_GRAPHS, 128, 0, stream>>>(pool, gcnt, Wc1, bc1, Wc2, bc2, out);
}

// Round 5
// 2634.707 us; speedup vs baseline: 1.1677x; 1.1677x over previous
//
#include <hip/hip_runtime.h>

// R4: restore R1 fused kernel (best: 2501us) + one-time per-node neighbor sort
// after CSR fill. Sorted adjacency => all concurrent rows sweep sources in
// ascending order => moving ~12MB band => partial L2 temporal reuse (today: 0,
// FETCH=442MB = 8 XCD x 51.2MB compulsory floor). Predict FETCH 442->300-360MB,
// layer 220->180-200us if fetch-throughput-bound (R3: gather ceiling 2.9 TB/s).

#define N_NODES 100000
#define N_EDGES 1600000
#define HID 128
#define NUM_LAYERS 10
#define NUM_GRAPHS 64
#define SCAN_BLOCKS ((N_NODES + 255) / 256)
#define ROWS 32        // nodes per block: 20 KB LDS
#define IDX_CAP 1024   // LDS-staged neighbor indices per 32-node block (mean 512)

// ---------------- CSR build ----------------

__global__ __launch_bounds__(256) void count_deg_kernel(const int* __restrict__ dst,
                                                        int* __restrict__ deg, int E) {
  int e = blockIdx.x * 256 + threadIdx.x;
  if (e < E) atomicAdd(&deg[dst[e]], 1);
}

__global__ __launch_bounds__(256) void block_sum_kernel(const int* __restrict__ deg,
                                                        int* __restrict__ psum, int n) {
  __shared__ int sd[256];
  int i = blockIdx.x * 256 + threadIdx.x;
  sd[threadIdx.x] = (i < n) ? deg[i] : 0;
  __syncthreads();
  for (int off = 128; off > 0; off >>= 1) {
    if (threadIdx.x < off) sd[threadIdx.x] += sd[threadIdx.x + off];
    __syncthreads();
  }
  if (threadIdx.x == 0) psum[blockIdx.x] = sd[0];
}

__global__ __launch_bounds__(512) void scan_partials_kernel(const int* __restrict__ psum,
                                                            int* __restrict__ poff, int nb) {
  __shared__ int sd[512];
  int i = threadIdx.x;
  int v = (i < nb) ? psum[i] : 0;
  sd[i] = v;
  __syncthreads();
  for (int off = 1; off < 512; off <<= 1) {
    int t = (i >= off) ? sd[i - off] : 0;
    __syncthreads();
    sd[i] += t;
    __syncthreads();
  }
  if (i < nb) poff[i] = sd[i] - v;  // exclusive
}

__global__ __launch_bounds__(256) void write_rs_kernel(const int* __restrict__ deg,
                                                       const int* __restrict__ poff,
                                                       int* __restrict__ rs,
                                                       int* __restrict__ cur, int n) {
  __shared__ int sd[256];
  int i = blockIdx.x * 256 + threadIdx.x;
  int v = (i < n) ? deg[i] : 0;
  sd[threadIdx.x] = v;
  __syncthreads();
  for (int off = 1; off < 256; off <<= 1) {
    int t = (threadIdx.x >= off) ? sd[threadIdx.x - off] : 0;
    __syncthreads();
    sd[threadIdx.x] += t;
    __syncthreads();
  }
  if (i < n) {
    int incl = poff[blockIdx.x] + sd[threadIdx.x];
    rs[i + 1] = incl;
    cur[i] = incl - v;
  }
  if (i == 0) rs[0] = 0;
}

__global__ __launch_bounds__(256) void fill_csr_kernel(const int* __restrict__ src,
                                                       const int* __restrict__ dst,
                                                       int* __restrict__ cur,
                                                       int* __restrict__ csr, int E) {
  int e = blockIdx.x * 256 + threadIdx.x;
  if (e < E) {
    int p = atomicAdd(&cur[dst[e]], 1);
    csr[p] = src[e];
  }
}

// One-time: sort each node's neighbor list ascending (insertion sort, ~16 elems).
// Gives all concurrent gather rows an aligned ascending source sweep -> L2 band reuse.
__global__ __launch_bounds__(256) void sort_adj_kernel(const int* __restrict__ rs,
                                                       int* __restrict__ csr, int n) {
  int v = blockIdx.x * 256 + threadIdx.x;
  if (v >= n) return;
  int e0 = rs[v];
  int m = rs[v + 1] - e0;
  for (int i = 1; i < m; ++i) {
    int key = csr[e0 + i];
    int j = i - 1;
    while (j >= 0 && csr[e0 + j] > key) {
      csr[e0 + j + 1] = csr[e0 + j];
      --j;
    }
    csr[e0 + j + 1] = key;
  }
}

// ---------------- fused layer: gather + MLP (R1 structure) ----------------
// xout = relu( relu(h@W1+b1)@W2 + b2 [+h] ) + xin,  h = (1+eps)*xin + sum_{u->v} xin[u]

__global__ __launch_bounds__(256, 6) void layer_kernel(const float* __restrict__ xin,
                                                       float* __restrict__ xout,
                                                       const int* __restrict__ rs,
                                                       const int* __restrict__ csr,
                                                       const float* __restrict__ eps, int layer,
                                                       const float* __restrict__ W1,
                                                       const float* __restrict__ b1,
                                                       const float* __restrict__ W2,
                                                       const float* __restrict__ b2,
                                                       int n, int addH) {
  __shared__ float lh[ROWS * 128];
  __shared__ int lidx[IDX_CAP];
  const int tid = threadIdx.x;
  const int row0 = blockIdx.x * ROWS;
  const float4* x4 = (const float4*)xin;
  float4* lh4 = (float4*)lh;
  const float s = 1.0f + eps[layer];

  // ---- Phase 0: stage this block's CSR index range into LDS (coalesced).
  int rowEnd = row0 + ROWS; if (rowEnd > n) rowEnd = n;
  const int eBase = rs[row0];
  const int cnt = rs[rowEnd] - eBase;
  const int stage = (cnt < IDX_CAP) ? cnt : IDX_CAP;
  for (int t = tid; t < stage; t += 256) lidx[t] = csr[eBase + t];
  __syncthreads();

  // ---- Phase 1: gather h-tile into LDS. 8 nodes at a time, 32 lanes/node.
  const int w = tid >> 5;
  const int lane = tid & 31;
#pragma unroll
  for (int it = 0; it < ROWS / 8; ++it) {
    int li = it * 8 + w;          // local row 0..31
    int node = row0 + li;
    float ax = 0.f, ay = 0.f, az = 0.f, aw = 0.f;
    if (node < n) {
      float4 v = x4[node * 32 + lane];
      ax = v.x * s; ay = v.y * s; az = v.z * s; aw = v.w * s;
      const int e0 = rs[node];
      const int m = rs[node + 1] - e0;
      const int lb = e0 - eBase;
      int i = 0;
      if (lb + m <= stage) {
        // fast path: all indices in LDS
        for (; i + 8 <= m; i += 8) {
          int u0 = lidx[lb + i + 0], u1 = lidx[lb + i + 1];
          int u2 = lidx[lb + i + 2], u3 = lidx[lb + i + 3];
          int u4 = lidx[lb + i + 4], u5 = lidx[lb + i + 5];
          int u6 = lidx[lb + i + 6], u7 = lidx[lb + i + 7];
          float4 t0 = x4[u0 * 32 + lane];
          float4 t1 = x4[u1 * 32 + lane];
          float4 t2 = x4[u2 * 32 + lane];
          float4 t3 = x4[u3 * 32 + lane];
          float4 t4 = x4[u4 * 32 + lane];
          float4 t5 = x4[u5 * 32 + lane];
          float4 t6 = x4[u6 * 32 + lane];
          float4 t7 = x4[u7 * 32 + lane];
          ax += t0.x + t1.x + t2.x + t3.x + t4.x + t5.x + t6.x + t7.x;
          ay += t0.y + t1.y + t2.y + t3.y + t4.y + t5.y + t6.y + t7.y;
          az += t0.z + t1.z + t2.z + t3.z + t4.z + t5.z + t6.z + t7.z;
          aw += t0.w + t1.w + t2.w + t3.w + t4.w + t5.w + t6.w + t7.w;
        }
        if (i + 4 <= m) {
          int u0 = lidx[lb + i + 0], u1 = lidx[lb + i + 1];
          int u2 = lidx[lb + i + 2], u3 = lidx[lb + i + 3];
          float4 t0 = x4[u0 * 32 + lane];
          float4 t1 = x4[u1 * 32 + lane];
          float4 t2 = x4[u2 * 32 + lane];
          float4 t3 = x4[u3 * 32 + lane];
          ax += t0.x + t1.x + t2.x + t3.x;
          ay += t0.y + t1.y + t2.y + t3.y;
          az += t0.z + t1.z + t2.z + t3.z;
          aw += t0.w + t1.w + t2.w + t3.w;
          i += 4;
        }
        if (i + 2 <= m) {
          int u0 = lidx[lb + i + 0], u1 = lidx[lb + i + 1];
          float4 t0 = x4[u0 * 32 + lane];
          float4 t1 = x4[u1 * 32 + lane];
          ax += t0.x + t1.x; ay += t0.y + t1.y;
          az += t0.z + t1.z; aw += t0.w + t1.w;
          i += 2;
        }
        if (i < m) {
          int u = lidx[lb + i];
          float4 t = x4[u * 32 + lane];
          ax += t.x; ay += t.y; az += t.z; aw += t.w;
        }
      } else {
        // slow fallback (never taken for this input's degree distribution)
        for (; i < m; ++i) {
          int u = csr[e0 + i];
          float4 t = x4[u * 32 + lane];
          ax += t.x; ay += t.y; az += t.z; aw += t.w;
        }
      }
    }
    float4 r; r.x = ax; r.y = ay; r.z = az; r.w = aw;
    lh4[li * 32 + lane] = r;
  }
  __syncthreads();

  // ---- Phase 2: GEMM1 (mid = relu(h@W1+b1)); thread (rg,cg) owns rows rg*4+r, cols cg*4..
  const int cg = tid & 31;
  const int rg = tid >> 5;
  float acc[4][4];
#pragma unroll
  for (int r = 0; r < 4; ++r) { acc[r][0] = acc[r][1] = acc[r][2] = acc[r][3] = 0.f; }

  for (int k4 = 0; k4 < 32; ++k4) {
    float4 w0 = *(const float4*)(W1 + (k4 * 4 + 0) * 128 + cg * 4);
    float4 w1 = *(const float4*)(W1 + (k4 * 4 + 1) * 128 + cg * 4);
    float4 w2 = *(const float4*)(W1 + (k4 * 4 + 2) * 128 + cg * 4);
    float4 w3 = *(const float4*)(W1 + (k4 * 4 + 3) * 128 + cg * 4);
#pragma unroll
    for (int r = 0; r < 4; ++r) {
      float4 a = *(const float4*)(lh + (rg * 4 + r) * 128 + k4 * 4);
      acc[r][0] += a.x * w0.x + a.y * w1.x + a.z * w2.x + a.w * w3.x;
      acc[r][1] += a.x * w0.y + a.y * w1.y + a.z * w2.y + a.w * w3.y;
      acc[r][2] += a.x * w0.z + a.y * w1.z + a.z * w2.z + a.w * w3.z;
      acc[r][3] += a.x * w0.w + a.y * w1.w + a.z * w2.w + a.w * w3.w;
    }
  }

  // snapshot h values needed in epilogue (before lh is overwritten by mid)
  float4 hreg[4];
#pragma unroll
  for (int r = 0; r < 4; ++r) hreg[r] = *(const float4*)(lh + (rg * 4 + r) * 128 + cg * 4);
  __syncthreads();

  {
    float4 bb = *(const float4*)(b1 + cg * 4);
#pragma unroll
    for (int r = 0; r < 4; ++r) {
      float4 o;
      o.x = fmaxf(acc[r][0] + bb.x, 0.f);
      o.y = fmaxf(acc[r][1] + bb.y, 0.f);
      o.z = fmaxf(acc[r][2] + bb.z, 0.f);
      o.w = fmaxf(acc[r][3] + bb.w, 0.f);
      *(float4*)(lh + (rg * 4 + r) * 128 + cg * 4) = o;
      acc[r][0] = acc[r][1] = acc[r][2] = acc[r][3] = 0.f;
    }
  }
  __syncthreads();

  // ---- Phase 3: GEMM2 (out = mid@W2 + b2)
  for (int k4 = 0; k4 < 32; ++k4) {
    float4 w0 = *(const float4*)(W2 + (k4 * 4 + 0) * 128 + cg * 4);
    float4 w1 = *(const float4*)(W2 + (k4 * 4 + 1) * 128 + cg * 4);
    float4 w2 = *(const float4*)(W2 + (k4 * 4 + 2) * 128 + cg * 4);
    float4 w3 = *(const float4*)(W2 + (k4 * 4 + 3) * 128 + cg * 4);
#pragma unroll
    for (int r = 0; r < 4; ++r) {
      float4 a = *(const float4*)(lh + (rg * 4 + r) * 128 + k4 * 4);
      acc[r][0] += a.x * w0.x + a.y * w1.x + a.z * w2.x + a.w * w3.x;
      acc[r][1] += a.x * w0.y + a.y * w1.y + a.z * w2.y + a.w * w3.y;
      acc[r][2] += a.x * w0.z + a.y * w1.z + a.z * w2.z + a.w * w3.z;
      acc[r][3] += a.x * w0.w + a.y * w1.w + a.z * w2.w + a.w * w3.w;
    }
  }

  // ---- Epilogue: +b2 (+h) -> relu -> +xin, write xout
  float4 b2v = *(const float4*)(b2 + cg * 4);
  float4* xo4 = (float4*)xout;
#pragma unroll
  for (int r = 0; r < 4; ++r) {
    int row = row0 + rg * 4 + r;
    if (row < n) {
      float ox = acc[r][0] + b2v.x;
      float oy = acc[r][1] + b2v.y;
      float oz = acc[r][2] + b2v.z;
      float ow = acc[r][3] + b2v.w;
      if (addH) {
        ox += hreg[r].x; oy += hreg[r].y; oz += hreg[r].z; ow += hreg[r].w;
      }
      ox = fmaxf(ox, 0.f); oy = fmaxf(oy, 0.f); oz = fmaxf(oz, 0.f); ow = fmaxf(ow, 0.f);
      float4 xv = x4[row * 32 + cg];
      float4 o;
      o.x = ox + xv.x; o.y = oy + xv.y; o.z = oz + xv.z; o.w = ow + xv.w;
      xo4[row * 32 + cg] = o;
    }
  }
}

// ---------------- pooling (batch is sorted) ----------------

__global__ __launch_bounds__(128) void pool_kernel(const float* __restrict__ x,
                                                   const int* __restrict__ batch,
                                                   float* __restrict__ pool,
                                                   int* __restrict__ gcnt, int n) {
  const int CH = 512;
  int c = threadIdx.x;
  int n0 = blockIdx.x * CH;
  if (n0 >= n) return;
  int n1 = n0 + CH; if (n1 > n) n1 = n;
  float acc = 0.f;
  int g = batch[n0];
  int cl = 0;
  for (int i = n0; i < n1; ++i) {
    int gi = batch[i];
    if (gi != g) {
      atomicAdd(&pool[g * 128 + c], acc);
      if (c == 0) atomicAdd(&gcnt[g], cl);
      acc = 0.f; cl = 0; g = gi;
    }
    acc += x[i * 128 + c];
    cl++;
  }
  atomicAdd(&pool[g * 128 + c], acc);
  if (c == 0) atomicAdd(&gcnt[g], cl);
}

// ---------------- classifier: one block per graph ----------------

__global__ __launch_bounds__(128) void classifier_kernel(const float* __restrict__ pool,
                                                         const int* __restrict__ gcnt,
                                                         const float* __restrict__ Wc1,
                                                         const float* __restrict__ bc1,
                                                         const float* __restrict__ Wc2,
                                                         const float* __restrict__ bc2,
                                                         float* __restrict__ out) {
  __shared__ float prow[128];
  __shared__ float hid[128];
  int g = blockIdx.x;
  int c = threadIdx.x;
  float cf = (float)gcnt[g];
  if (cf < 1.f) cf = 1.f;
  prow[c] = pool[g * 128 + c] / cf;
  __syncthreads();
  float a = bc1[c];
  for (int k = 0; k < 128; ++k) a += prow[k] * Wc1[k * 128 + c];
  hid[c] = fmaxf(a, 0.f);
  __syncthreads();
  if (c < 2) {
    float a2 = bc2[c];
    for (int k = 0; k < 128; ++k) a2 += hid[k] * Wc2[k * 2 + c];
    out[g * 2 + c] = a2;
  }
}

// ---------------- launch ----------------

extern "C" void kernel_launch(void* const* d_in, const int* in_sizes, int n_in,
                              void* d_out, int out_size, void* d_ws, size_t ws_size,
                              hipStream_t stream) {
  const float* x_in = (const float*)d_in[0];
  const int* edge_index = (const int*)d_in[1];
  const int* batch = (const int*)d_in[2];
  const float* eps = (const float*)d_in[3];
  const float* W1 = (const float*)d_in[4];
  const float* b1 = (const float*)d_in[5];
  const float* W2 = (const float*)d_in[6];
  const float* b2 = (const float*)d_in[7];
  const float* Wc1 = (const float*)d_in[8];
  const float* bc1 = (const float*)d_in[9];
  const float* Wc2 = (const float*)d_in[10];
  const float* bc2 = (const float*)d_in[11];
  float* out = (float*)d_out;

  const int N = N_NODES, E = N_EDGES;
  const int* src = edge_index;
  const int* dst = edge_index + E;

  // workspace layout
  float* xa = (float*)d_ws;                    // N*128 floats
  float* xb = xa + (size_t)N * 128;            // N*128 floats
  int* deg = (int*)(xb + (size_t)N * 128);     // N
  int* rs = deg + N;                           // N+1
  int* cur = rs + (N + 1);                     // N
  int* csr = cur + N;                          // E
  float* pool = (float*)(csr + E);             // 64*128
  int* gcnt = (int*)(pool + NUM_GRAPHS * 128); // 64
  int* psum = gcnt + NUM_GRAPHS;               // SCAN_BLOCKS
  int* poff = psum + SCAN_BLOCKS;              // SCAN_BLOCKS

  hipMemsetAsync(deg, 0, N * sizeof(int), stream);

  // CSR build
  count_deg_kernel<<<(E + 255) / 256, 256, 0, stream>>>(dst, deg, E);
  block_sum_kernel<<<SCAN_BLOCKS, 256, 0, stream>>>(deg, psum, N);
  scan_partials_kernel<<<1, 512, 0, stream>>>(psum, poff, SCAN_BLOCKS);
  write_rs_kernel<<<SCAN_BLOCKS, 256, 0, stream>>>(deg, poff, rs, cur, N);
  fill_csr_kernel<<<(E + 255) / 256, 256, 0, stream>>>(src, dst, cur, csr, E);
  sort_adj_kernel<<<SCAN_BLOCKS, 256, 0, stream>>>(rs, csr, N);

  // layers (ping-pong; layer 0 reads the input buffer directly)
  for (int i = 0; i < NUM_LAYERS; ++i) {
    const float* xi = (i == 0) ? x_in : ((i % 2 == 0) ? xb : xa);
    float* xo = (i % 2 == 0) ? xa : xb;
    layer_kernel<<<(N + ROWS - 1) / ROWS, 256, 0, stream>>>(xi, xo, rs, csr, eps, i,
                                                    W1 + (size_t)i * 128 * 128, b1 + (size_t)i * 128,
                                                    W2 + (size_t)i * 128 * 128, b2 + (size_t)i * 128,
                                                    N, i > 0 ? 1 : 0);
  }
  const float* xfin = (NUM_LAYERS % 2 == 0) ? xb : xa;

  // pooling + classifier
  hipMemsetAsync(pool, 0, NUM_GRAPHS * 128 * sizeof(float), stream);
  hipMemsetAsync(gcnt, 0, NUM_GRAPHS * sizeof(int), stream);
  pool_kernel<<<(N + 511) / 512, 128, 0, stream>>>(xfin, batch, pool, gcnt, N);
  classifier_kernel<<<NUM_GRAPHS, 128, 0, stream>>>(pool, gcnt, Wc1, bc1, Wc2, bc2, out);
}

// Round 6
// 2569.199 us; speedup vs baseline: 1.1974x; 1.0255x over previous
//
#include <hip/hip_runtime.h>

// R5: exact R1 fused kernel (best verified: 2501us) with __launch_bounds__(256,8).
// R1 measured VGPR=40 / LDS=20480 -> 8 blocks/CU fit (160KB LDS, VGPR<=64) but
// (256,6) capped occupancy at 57%. R3 showed pure gather at 8 blocks/CU serves
// 2.9 TB/s vs R1's fused 2.45. Sort kernel dropped (R4: FETCH unchanged 442MB,
// falsified). Predict: occ 57->75+%, layer 220->185-200us, FETCH ~442MB,
// VGPR<=64 no scratch, total ~2200-2300us.

#define N_NODES 100000
#define N_EDGES 1600000
#define HID 128
#define NUM_LAYERS 10
#define NUM_GRAPHS 64
#define SCAN_BLOCKS ((N_NODES + 255) / 256)
#define ROWS 32        // nodes per block: 20 KB LDS -> 8 blocks/CU at (256,8)
#define IDX_CAP 1024   // LDS-staged neighbor indices per 32-node block (mean 512)

// ---------------- CSR build ----------------

__global__ __launch_bounds__(256) void count_deg_kernel(const int* __restrict__ dst,
                                                        int* __restrict__ deg, int E) {
  int e = blockIdx.x * 256 + threadIdx.x;
  if (e < E) atomicAdd(&deg[dst[e]], 1);
}

__global__ __launch_bounds__(256) void block_sum_kernel(const int* __restrict__ deg,
                                                        int* __restrict__ psum, int n) {
  __shared__ int sd[256];
  int i = blockIdx.x * 256 + threadIdx.x;
  sd[threadIdx.x] = (i < n) ? deg[i] : 0;
  __syncthreads();
  for (int off = 128; off > 0; off >>= 1) {
    if (threadIdx.x < off) sd[threadIdx.x] += sd[threadIdx.x + off];
    __syncthreads();
  }
  if (threadIdx.x == 0) psum[blockIdx.x] = sd[0];
}

__global__ __launch_bounds__(512) void scan_partials_kernel(const int* __restrict__ psum,
                                                            int* __restrict__ poff, int nb) {
  __shared__ int sd[512];
  int i = threadIdx.x;
  int v = (i < nb) ? psum[i] : 0;
  sd[i] = v;
  __syncthreads();
  for (int off = 1; off < 512; off <<= 1) {
    int t = (i >= off) ? sd[i - off] : 0;
    __syncthreads();
    sd[i] += t;
    __syncthreads();
  }
  if (i < nb) poff[i] = sd[i] - v;  // exclusive
}

__global__ __launch_bounds__(256) void write_rs_kernel(const int* __restrict__ deg,
                                                       const int* __restrict__ poff,
                                                       int* __restrict__ rs,
                                                       int* __restrict__ cur, int n) {
  __shared__ int sd[256];
  int i = blockIdx.x * 256 + threadIdx.x;
  int v = (i < n) ? deg[i] : 0;
  sd[threadIdx.x] = v;
  __syncthreads();
  for (int off = 1; off < 256; off <<= 1) {
    int t = (threadIdx.x >= off) ? sd[threadIdx.x - off] : 0;
    __syncthreads();
    sd[threadIdx.x] += t;
    __syncthreads();
  }
  if (i < n) {
    int incl = poff[blockIdx.x] + sd[threadIdx.x];
    rs[i + 1] = incl;
    cur[i] = incl - v;
  }
  if (i == 0) rs[0] = 0;
}

__global__ __launch_bounds__(256) void fill_csr_kernel(const int* __restrict__ src,
                                                       const int* __restrict__ dst,
                                                       int* __restrict__ cur,
                                                       int* __restrict__ csr, int E) {
  int e = blockIdx.x * 256 + threadIdx.x;
  if (e < E) {
    int p = atomicAdd(&cur[dst[e]], 1);
    csr[p] = src[e];
  }
}

// ---------------- fused layer: gather + MLP ----------------
// xout = relu( relu(h@W1+b1)@W2 + b2 [+h] ) + xin,  h = (1+eps)*xin + sum_{u->v} xin[u]

__global__ __launch_bounds__(256, 8) void layer_kernel(const float* __restrict__ xin,
                                                       float* __restrict__ xout,
                                                       const int* __restrict__ rs,
                                                       const int* __restrict__ csr,
                                                       const float* __restrict__ eps, int layer,
                                                       const float* __restrict__ W1,
                                                       const float* __restrict__ b1,
                                                       const float* __restrict__ W2,
                                                       const float* __restrict__ b2,
                                                       int n, int addH) {
  __shared__ float lh[ROWS * 128];
  __shared__ int lidx[IDX_CAP];
  const int tid = threadIdx.x;
  const int row0 = blockIdx.x * ROWS;
  const float4* x4 = (const float4*)xin;
  float4* lh4 = (float4*)lh;
  const float s = 1.0f + eps[layer];

  // ---- Phase 0: stage this block's CSR index range into LDS (coalesced).
  int rowEnd = row0 + ROWS; if (rowEnd > n) rowEnd = n;
  const int eBase = rs[row0];
  const int cnt = rs[rowEnd] - eBase;
  const int stage = (cnt < IDX_CAP) ? cnt : IDX_CAP;
  for (int t = tid; t < stage; t += 256) lidx[t] = csr[eBase + t];
  __syncthreads();

  // ---- Phase 1: gather h-tile into LDS. 8 nodes at a time, 32 lanes/node.
  const int w = tid >> 5;
  const int lane = tid & 31;
#pragma unroll
  for (int it = 0; it < ROWS / 8; ++it) {
    int li = it * 8 + w;          // local row 0..31
    int node = row0 + li;
    float ax = 0.f, ay = 0.f, az = 0.f, aw = 0.f;
    if (node < n) {
      float4 v = x4[node * 32 + lane];
      ax = v.x * s; ay = v.y * s; az = v.z * s; aw = v.w * s;
      const int e0 = rs[node];
      const int m = rs[node + 1] - e0;
      const int lb = e0 - eBase;
      int i = 0;
      if (lb + m <= stage) {
        // fast path: all indices in LDS
        for (; i + 8 <= m; i += 8) {
          int u0 = lidx[lb + i + 0], u1 = lidx[lb + i + 1];
          int u2 = lidx[lb + i + 2], u3 = lidx[lb + i + 3];
          int u4 = lidx[lb + i + 4], u5 = lidx[lb + i + 5];
          int u6 = lidx[lb + i + 6], u7 = lidx[lb + i + 7];
          float4 t0 = x4[u0 * 32 + lane];
          float4 t1 = x4[u1 * 32 + lane];
          float4 t2 = x4[u2 * 32 + lane];
          float4 t3 = x4[u3 * 32 + lane];
          float4 t4 = x4[u4 * 32 + lane];
          float4 t5 = x4[u5 * 32 + lane];
          float4 t6 = x4[u6 * 32 + lane];
          float4 t7 = x4[u7 * 32 + lane];
          ax += t0.x + t1.x + t2.x + t3.x + t4.x + t5.x + t6.x + t7.x;
          ay += t0.y + t1.y + t2.y + t3.y + t4.y + t5.y + t6.y + t7.y;
          az += t0.z + t1.z + t2.z + t3.z + t4.z + t5.z + t6.z + t7.z;
          aw += t0.w + t1.w + t2.w + t3.w + t4.w + t5.w + t6.w + t7.w;
        }
        if (i + 4 <= m) {
          int u0 = lidx[lb + i + 0], u1 = lidx[lb + i + 1];
          int u2 = lidx[lb + i + 2], u3 = lidx[lb + i + 3];
          float4 t0 = x4[u0 * 32 + lane];
          float4 t1 = x4[u1 * 32 + lane];
          float4 t2 = x4[u2 * 32 + lane];
          float4 t3 = x4[u3 * 32 + lane];
          ax += t0.x + t1.x + t2.x + t3.x;
          ay += t0.y + t1.y + t2.y + t3.y;
          az += t0.z + t1.z + t2.z + t3.z;
          aw += t0.w + t1.w + t2.w + t3.w;
          i += 4;
        }
        if (i + 2 <= m) {
          int u0 = lidx[lb + i + 0], u1 = lidx[lb + i + 1];
          float4 t0 = x4[u0 * 32 + lane];
          float4 t1 = x4[u1 * 32 + lane];
          ax += t0.x + t1.x; ay += t0.y + t1.y;
          az += t0.z + t1.z; aw += t0.w + t1.w;
          i += 2;
        }
        if (i < m) {
          int u = lidx[lb + i];
          float4 t = x4[u * 32 + lane];
          ax += t.x; ay += t.y; az += t.z; aw += t.w;
        }
      } else {
        // slow fallback (never taken for this input's degree distribution)
        for (; i < m; ++i) {
          int u = csr[e0 + i];
          float4 t = x4[u * 32 + lane];
          ax += t.x; ay += t.y; az += t.z; aw += t.w;
        }
      }
    }
    float4 r; r.x = ax; r.y = ay; r.z = az; r.w = aw;
    lh4[li * 32 + lane] = r;
  }
  __syncthreads();

  // ---- Phase 2: GEMM1 (mid = relu(h@W1+b1)); thread (rg,cg) owns rows rg*4+r, cols cg*4..
  const int cg = tid & 31;
  const int rg = tid >> 5;
  float acc[4][4];
#pragma unroll
  for (int r = 0; r < 4; ++r) { acc[r][0] = acc[r][1] = acc[r][2] = acc[r][3] = 0.f; }

  for (int k4 = 0; k4 < 32; ++k4) {
    float4 w0 = *(const float4*)(W1 + (k4 * 4 + 0) * 128 + cg * 4);
    float4 w1 = *(const float4*)(W1 + (k4 * 4 + 1) * 128 + cg * 4);
    float4 w2 = *(const float4*)(W1 + (k4 * 4 + 2) * 128 + cg * 4);
    float4 w3 = *(const float4*)(W1 + (k4 * 4 + 3) * 128 + cg * 4);
#pragma unroll
    for (int r = 0; r < 4; ++r) {
      float4 a = *(const float4*)(lh + (rg * 4 + r) * 128 + k4 * 4);
      acc[r][0] += a.x * w0.x + a.y * w1.x + a.z * w2.x + a.w * w3.x;
      acc[r][1] += a.x * w0.y + a.y * w1.y + a.z * w2.y + a.w * w3.y;
      acc[r][2] += a.x * w0.z + a.y * w1.z + a.z * w2.z + a.w * w3.z;
      acc[r][3] += a.x * w0.w + a.y * w1.w + a.z * w2.w + a.w * w3.w;
    }
  }

  // snapshot h values needed in epilogue (before lh is overwritten by mid)
  float4 hreg[4];
#pragma unroll
  for (int r = 0; r < 4; ++r) hreg[r] = *(const float4*)(lh + (rg * 4 + r) * 128 + cg * 4);
  __syncthreads();

  {
    float4 bb = *(const float4*)(b1 + cg * 4);
#pragma unroll
    for (int r = 0; r < 4; ++r) {
      float4 o;
      o.x = fmaxf(acc[r][0] + bb.x, 0.f);
      o.y = fmaxf(acc[r][1] + bb.y, 0.f);
      o.z = fmaxf(acc[r][2] + bb.z, 0.f);
      o.w = fmaxf(acc[r][3] + bb.w, 0.f);
      *(float4*)(lh + (rg * 4 + r) * 128 + cg * 4) = o;
      acc[r][0] = acc[r][1] = acc[r][2] = acc[r][3] = 0.f;
    }
  }
  __syncthreads();

  // ---- Phase 3: GEMM2 (out = mid@W2 + b2)
  for (int k4 = 0; k4 < 32; ++k4) {
    float4 w0 = *(const float4*)(W2 + (k4 * 4 + 0) * 128 + cg * 4);
    float4 w1 = *(const float4*)(W2 + (k4 * 4 + 1) * 128 + cg * 4);
    float4 w2 = *(const float4*)(W2 + (k4 * 4 + 2) * 128 + cg * 4);
    float4 w3 = *(const float4*)(W2 + (k4 * 4 + 3) * 128 + cg * 4);
#pragma unroll
    for (int r = 0; r < 4; ++r) {
      float4 a = *(const float4*)(lh + (rg * 4 + r) * 128 + k4 * 4);
      acc[r][0] += a.x * w0.x + a.y * w1.x + a.z * w2.x + a.w * w3.x;
      acc[r][1] += a.x * w0.y + a.y * w1.y + a.z * w2.y + a.w * w3.y;
      acc[r][2] += a.x * w0.z + a.y * w1.z + a.z * w2.z + a.w * w3.z;
      acc[r][3] += a.x * w0.w + a.y * w1.w + a.z * w2.w + a.w * w3.w;
    }
  }

  // ---- Epilogue: +b2 (+h) -> relu -> +xin, write xout
  float4 b2v = *(const float4*)(b2 + cg * 4);
  float4* xo4 = (float4*)xout;
#pragma unroll
  for (int r = 0; r < 4; ++r) {
    int row = row0 + rg * 4 + r;
    if (row < n) {
      float ox = acc[r][0] + b2v.x;
      float oy = acc[r][1] + b2v.y;
      float oz = acc[r][2] + b2v.z;
      float ow = acc[r][3] + b2v.w;
      if (addH) {
        ox += hreg[r].x; oy += hreg[r].y; oz += hreg[r].z; ow += hreg[r].w;
      }
      ox = fmaxf(ox, 0.f); oy = fmaxf(oy, 0.f); oz = fmaxf(oz, 0.f); ow = fmaxf(ow, 0.f);
      float4 xv = x4[row * 32 + cg];
      float4 o;
      o.x = ox + xv.x; o.y = oy + xv.y; o.z = oz + xv.z; o.w = ow + xv.w;
      xo4[row * 32 + cg] = o;
    }
  }
}

// ---------------- pooling (batch is sorted) ----------------

__global__ __launch_bounds__(128) void pool_kernel(const float* __restrict__ x,
                                                   const int* __restrict__ batch,
                                                   float* __restrict__ pool,
                                                   int* __restrict__ gcnt, int n) {
  const int CH = 512;
  int c = threadIdx.x;
  int n0 = blockIdx.x * CH;
  if (n0 >= n) return;
  int n1 = n0 + CH; if (n1 > n) n1 = n;
  float acc = 0.f;
  int g = batch[n0];
  int cl = 0;
  for (int i = n0; i < n1; ++i) {
    int gi = batch[i];
    if (gi != g) {
      atomicAdd(&pool[g * 128 + c], acc);
      if (c == 0) atomicAdd(&gcnt[g], cl);
      acc = 0.f; cl = 0; g = gi;
    }
    acc += x[i * 128 + c];
    cl++;
  }
  atomicAdd(&pool[g * 128 + c], acc);
  if (c == 0) atomicAdd(&gcnt[g], cl);
}

// ---------------- classifier: one block per graph ----------------

__global__ __launch_bounds__(128) void classifier_kernel(const float* __restrict__ pool,
                                                         const int* __restrict__ gcnt,
                                                         const float* __restrict__ Wc1,
                                                         const float* __restrict__ bc1,
                                                         const float* __restrict__ Wc2,
                                                         const float* __restrict__ bc2,
                                                         float* __restrict__ out) {
  __shared__ float prow[128];
  __shared__ float hid[128];
  int g = blockIdx.x;
  int c = threadIdx.x;
  float cf = (float)gcnt[g];
  if (cf < 1.f) cf = 1.f;
  prow[c] = pool[g * 128 + c] / cf;
  __syncthreads();
  float a = bc1[c];
  for (int k = 0; k < 128; ++k) a += prow[k] * Wc1[k * 128 + c];
  hid[c] = fmaxf(a, 0.f);
  __syncthreads();
  if (c < 2) {
    float a2 = bc2[c];
    for (int k = 0; k < 128; ++k) a2 += hid[k] * Wc2[k * 2 + c];
    out[g * 2 + c] = a2;
  }
}

// ---------------- launch ----------------

extern "C" void kernel_launch(void* const* d_in, const int* in_sizes, int n_in,
                              void* d_out, int out_size, void* d_ws, size_t ws_size,
                              hipStream_t stream) {
  const float* x_in = (const float*)d_in[0];
  const int* edge_index = (const int*)d_in[1];
  const int* batch = (const int*)d_in[2];
  const float* eps = (const float*)d_in[3];
  const float* W1 = (const float*)d_in[4];
  const float* b1 = (const float*)d_in[5];
  const float* W2 = (const float*)d_in[6];
  const float* b2 = (const float*)d_in[7];
  const float* Wc1 = (const float*)d_in[8];
  const float* bc1 = (const float*)d_in[9];
  const float* Wc2 = (const float*)d_in[10];
  const float* bc2 = (const float*)d_in[11];
  float* out = (float*)d_out;

  const int N = N_NODES, E = N_EDGES;
  const int* src = edge_index;
  const int* dst = edge_index + E;

  // workspace layout
  float* xa = (float*)d_ws;                    // N*128 floats
  float* xb = xa + (size_t)N * 128;            // N*128 floats
  int* deg = (int*)(xb + (size_t)N * 128);     // N
  int* rs = deg + N;                           // N+1
  int* cur = rs + (N + 1);                     // N
  int* csr = cur + N;                          // E
  float* pool = (float*)(csr + E);             // 64*128
  int* gcnt = (int*)(pool + NUM_GRAPHS * 128); // 64
  int* psum = gcnt + NUM_GRAPHS;               // SCAN_BLOCKS
  int* poff = psum + SCAN_BLOCKS;              // SCAN_BLOCKS

  hipMemsetAsync(deg, 0, N * sizeof(int), stream);

  // CSR build
  count_deg_kernel<<<(E + 255) / 256, 256, 0, stream>>>(dst, deg, E);
  block_sum_kernel<<<SCAN_BLOCKS, 256, 0, stream>>>(deg, psum, N);
  scan_partials_kernel<<<1, 512, 0, stream>>>(psum, poff, SCAN_BLOCKS);
  write_rs_kernel<<<SCAN_BLOCKS, 256, 0, stream>>>(deg, poff, rs, cur, N);
  fill_csr_kernel<<<(E + 255) / 256, 256, 0, stream>>>(src, dst, cur, csr, E);

  // layers (ping-pong; layer 0 reads the input buffer directly)
  for (int i = 0; i < NUM_LAYERS; ++i) {
    const float* xi = (i == 0) ? x_in : ((i % 2 == 0) ? xb : xa);
    float* xo = (i % 2 == 0) ? xa : xb;
    layer_kernel<<<(N + ROWS - 1) / ROWS, 256, 0, stream>>>(xi, xo, rs, csr, eps, i,
                                                    W1 + (size_t)i * 128 * 128, b1 + (size_t)i * 128,
                                                    W2 + (size_t)i * 128 * 128, b2 + (size_t)i * 128,
                                                    N, i > 0 ? 1 : 0);
  }
  const float* xfin = (NUM_LAYERS % 2 == 0) ? xb : xa;

  // pooling + classifier
  hipMemsetAsync(pool, 0, NUM_GRAPHS * 128 * sizeof(float), stream);
  hipMemsetAsync(gcnt, 0, NUM_GRAPHS * sizeof(int), stream);
  pool_kernel<<<(N + 511) / 512, 128, 0, stream>>>(xfin, batch, pool, gcnt, N);
  classifier_kernel<<<NUM_GRAPHS, 128, 0, stream>>>(pool, gcnt, Wc1, bc1, Wc2, bc2, out);
}

// Round 7
// 2300.577 us; speedup vs baseline: 1.3372x; 1.1168x over previous
//
#include <hip/hip_runtime.h>

// R6: bf16 neighbor-gather. Evidence: R1/R5 both plateau at ~2.45 TB/s TOTAL
// L2-miss bytes (530MB/220us vs 577MB/234us) despite 57 vs 75% occupancy ->
// byte-throughput-bound on XCD<->L3 fabric. Halve the dominant stream: neighbors
// read from a bf16 shadow of x (256B/row vs 512B). Self-term/residual/MLP stay
// fp32. fp32 state: single in-place buffer (own rows only); bf16 shadow
// ping-pongs. Predict: FETCH 442->270-300MB, WRITE ~100-115MB, layer 220->
// 160-180us, total ~1850-2050us. If FETCH drops but dur>=210: request-bound,
// revert. If passed=false: numerics, revert.

#define N_NODES 100000
#define N_EDGES 1600000
#define HID 128
#define NUM_LAYERS 10
#define NUM_GRAPHS 64
#define SCAN_BLOCKS ((N_NODES + 255) / 256)
#define ROWS 32        // nodes per block: 20 KB LDS
#define IDX_CAP 1024   // LDS-staged neighbor indices per 32-node block (mean 512)

typedef unsigned short ushort_t;

__device__ __forceinline__ float bf2f(unsigned short v) {
  return __uint_as_float(((unsigned)v) << 16);
}
__device__ __forceinline__ unsigned short f2bf(float f) {
  unsigned u = __float_as_uint(f);
  unsigned r = u + 0x7FFFu + ((u >> 16) & 1u);  // round-to-nearest-even
  return (unsigned short)(r >> 16);
}

// ---------------- CSR build ----------------

__global__ __launch_bounds__(256) void count_deg_kernel(const int* __restrict__ dst,
                                                        int* __restrict__ deg, int E) {
  int e = blockIdx.x * 256 + threadIdx.x;
  if (e < E) atomicAdd(&deg[dst[e]], 1);
}

__global__ __launch_bounds__(256) void block_sum_kernel(const int* __restrict__ deg,
                                                        int* __restrict__ psum, int n) {
  __shared__ int sd[256];
  int i = blockIdx.x * 256 + threadIdx.x;
  sd[threadIdx.x] = (i < n) ? deg[i] : 0;
  __syncthreads();
  for (int off = 128; off > 0; off >>= 1) {
    if (threadIdx.x < off) sd[threadIdx.x] += sd[threadIdx.x + off];
    __syncthreads();
  }
  if (threadIdx.x == 0) psum[blockIdx.x] = sd[0];
}

__global__ __launch_bounds__(512) void scan_partials_kernel(const int* __restrict__ psum,
                                                            int* __restrict__ poff, int nb) {
  __shared__ int sd[512];
  int i = threadIdx.x;
  int v = (i < nb) ? psum[i] : 0;
  sd[i] = v;
  __syncthreads();
  for (int off = 1; off < 512; off <<= 1) {
    int t = (i >= off) ? sd[i - off] : 0;
    __syncthreads();
    sd[i] += t;
    __syncthreads();
  }
  if (i < nb) poff[i] = sd[i] - v;  // exclusive
}

__global__ __launch_bounds__(256) void write_rs_kernel(const int* __restrict__ deg,
                                                       const int* __restrict__ poff,
                                                       int* __restrict__ rs,
                                                       int* __restrict__ cur, int n) {
  __shared__ int sd[256];
  int i = blockIdx.x * 256 + threadIdx.x;
  int v = (i < n) ? deg[i] : 0;
  sd[threadIdx.x] = v;
  __syncthreads();
  for (int off = 1; off < 256; off <<= 1) {
    int t = (threadIdx.x >= off) ? sd[threadIdx.x - off] : 0;
    __syncthreads();
    sd[threadIdx.x] += t;
    __syncthreads();
  }
  if (i < n) {
    int incl = poff[blockIdx.x] + sd[threadIdx.x];
    rs[i + 1] = incl;
    cur[i] = incl - v;
  }
  if (i == 0) rs[0] = 0;
}

__global__ __launch_bounds__(256) void fill_csr_kernel(const int* __restrict__ src,
                                                       const int* __restrict__ dst,
                                                       int* __restrict__ cur,
                                                       int* __restrict__ csr, int E) {
  int e = blockIdx.x * 256 + threadIdx.x;
  if (e < E) {
    int p = atomicAdd(&cur[dst[e]], 1);
    csr[p] = src[e];
  }
}

// one-time: bf16 shadow of the input features
__global__ __launch_bounds__(256) void cast_bf16_kernel(const float* __restrict__ xin,
                                                        ushort_t* __restrict__ xh, int n4) {
  int i = blockIdx.x * 256 + threadIdx.x;
  if (i < n4) {
    float4 v = ((const float4*)xin)[i];
    ushort4 o;
    o.x = f2bf(v.x); o.y = f2bf(v.y); o.z = f2bf(v.z); o.w = f2bf(v.w);
    ((ushort4*)xh)[i] = o;
  }
}

// ---------------- fused layer: gather + MLP ----------------
// xout = relu( relu(h@W1+b1)@W2 + b2 [+h] ) + xin,  h = (1+eps)*xin + sum_{u->v} bf16(xin[u])
// fp32 state in-place (each block touches only its own rows); neighbor reads hit
// the bf16 shadow (xh_in), epilogue writes next layer's shadow (xh_out).

__global__ __launch_bounds__(256, 6) void layer_kernel(const float* __restrict__ xin,
                                                       float* __restrict__ xout,
                                                       const ushort_t* __restrict__ xh_in,
                                                       ushort_t* __restrict__ xh_out,
                                                       const int* __restrict__ rs,
                                                       const int* __restrict__ csr,
                                                       const float* __restrict__ eps, int layer,
                                                       const float* __restrict__ W1,
                                                       const float* __restrict__ b1,
                                                       const float* __restrict__ W2,
                                                       const float* __restrict__ b2,
                                                       int n, int addH) {
  __shared__ float lh[ROWS * 128];
  __shared__ int lidx[IDX_CAP];
  const int tid = threadIdx.x;
  const int row0 = blockIdx.x * ROWS;
  const float4* x4 = (const float4*)xin;
  const ushort4* xh4 = (const ushort4*)xh_in;
  float4* lh4 = (float4*)lh;
  const float s = 1.0f + eps[layer];

  // ---- Phase 0: stage this block's CSR index range into LDS (coalesced).
  int rowEnd = row0 + ROWS; if (rowEnd > n) rowEnd = n;
  const int eBase = rs[row0];
  const int cnt = rs[rowEnd] - eBase;
  const int stage = (cnt < IDX_CAP) ? cnt : IDX_CAP;
  for (int t = tid; t < stage; t += 256) lidx[t] = csr[eBase + t];
  __syncthreads();

  // ---- Phase 1: gather h-tile into LDS. 8 nodes at a time, 32 lanes/node.
  const int w = tid >> 5;
  const int lane = tid & 31;
#pragma unroll
  for (int it = 0; it < ROWS / 8; ++it) {
    int li = it * 8 + w;          // local row 0..31
    int node = row0 + li;
    float ax = 0.f, ay = 0.f, az = 0.f, aw = 0.f;
    if (node < n) {
      float4 v = x4[node * 32 + lane];        // self term: fp32, own row
      ax = v.x * s; ay = v.y * s; az = v.z * s; aw = v.w * s;
      const int e0 = rs[node];
      const int m = rs[node + 1] - e0;
      const int lb = e0 - eBase;
      int i = 0;
      if (lb + m <= stage) {
        // fast path: all indices in LDS; neighbor rows from bf16 shadow (8B/lane)
        for (; i + 8 <= m; i += 8) {
          int u0 = lidx[lb + i + 0], u1 = lidx[lb + i + 1];
          int u2 = lidx[lb + i + 2], u3 = lidx[lb + i + 3];
          int u4 = lidx[lb + i + 4], u5 = lidx[lb + i + 5];
          int u6 = lidx[lb + i + 6], u7 = lidx[lb + i + 7];
          ushort4 t0 = xh4[u0 * 32 + lane];
          ushort4 t1 = xh4[u1 * 32 + lane];
          ushort4 t2 = xh4[u2 * 32 + lane];
          ushort4 t3 = xh4[u3 * 32 + lane];
          ushort4 t4 = xh4[u4 * 32 + lane];
          ushort4 t5 = xh4[u5 * 32 + lane];
          ushort4 t6 = xh4[u6 * 32 + lane];
          ushort4 t7 = xh4[u7 * 32 + lane];
          ax += bf2f(t0.x) + bf2f(t1.x) + bf2f(t2.x) + bf2f(t3.x)
              + bf2f(t4.x) + bf2f(t5.x) + bf2f(t6.x) + bf2f(t7.x);
          ay += bf2f(t0.y) + bf2f(t1.y) + bf2f(t2.y) + bf2f(t3.y)
              + bf2f(t4.y) + bf2f(t5.y) + bf2f(t6.y) + bf2f(t7.y);
          az += bf2f(t0.z) + bf2f(t1.z) + bf2f(t2.z) + bf2f(t3.z)
              + bf2f(t4.z) + bf2f(t5.z) + bf2f(t6.z) + bf2f(t7.z);
          aw += bf2f(t0.w) + bf2f(t1.w) + bf2f(t2.w) + bf2f(t3.w)
              + bf2f(t4.w) + bf2f(t5.w) + bf2f(t6.w) + bf2f(t7.w);
        }
        if (i + 4 <= m) {
          int u0 = lidx[lb + i + 0], u1 = lidx[lb + i + 1];
          int u2 = lidx[lb + i + 2], u3 = lidx[lb + i + 3];
          ushort4 t0 = xh4[u0 * 32 + lane];
          ushort4 t1 = xh4[u1 * 32 + lane];
          ushort4 t2 = xh4[u2 * 32 + lane];
          ushort4 t3 = xh4[u3 * 32 + lane];
          ax += bf2f(t0.x) + bf2f(t1.x) + bf2f(t2.x) + bf2f(t3.x);
          ay += bf2f(t0.y) + bf2f(t1.y) + bf2f(t2.y) + bf2f(t3.y);
          az += bf2f(t0.z) + bf2f(t1.z) + bf2f(t2.z) + bf2f(t3.z);
          aw += bf2f(t0.w) + bf2f(t1.w) + bf2f(t2.w) + bf2f(t3.w);
          i += 4;
        }
        if (i + 2 <= m) {
          int u0 = lidx[lb + i + 0], u1 = lidx[lb + i + 1];
          ushort4 t0 = xh4[u0 * 32 + lane];
          ushort4 t1 = xh4[u1 * 32 + lane];
          ax += bf2f(t0.x) + bf2f(t1.x); ay += bf2f(t0.y) + bf2f(t1.y);
          az += bf2f(t0.z) + bf2f(t1.z); aw += bf2f(t0.w) + bf2f(t1.w);
          i += 2;
        }
        if (i < m) {
          int u = lidx[lb + i];
          ushort4 t = xh4[u * 32 + lane];
          ax += bf2f(t.x); ay += bf2f(t.y); az += bf2f(t.z); aw += bf2f(t.w);
        }
      } else {
        // slow fallback (never taken for this input's degree distribution)
        for (; i < m; ++i) {
          int u = csr[e0 + i];
          ushort4 t = xh4[u * 32 + lane];
          ax += bf2f(t.x); ay += bf2f(t.y); az += bf2f(t.z); aw += bf2f(t.w);
        }
      }
    }
    float4 r; r.x = ax; r.y = ay; r.z = az; r.w = aw;
    lh4[li * 32 + lane] = r;
  }
  __syncthreads();

  // ---- Phase 2: GEMM1 (mid = relu(h@W1+b1)); thread (rg,cg) owns rows rg*4+r, cols cg*4..
  const int cg = tid & 31;
  const int rg = tid >> 5;
  float acc[4][4];
#pragma unroll
  for (int r = 0; r < 4; ++r) { acc[r][0] = acc[r][1] = acc[r][2] = acc[r][3] = 0.f; }

  for (int k4 = 0; k4 < 32; ++k4) {
    float4 w0 = *(const float4*)(W1 + (k4 * 4 + 0) * 128 + cg * 4);
    float4 w1 = *(const float4*)(W1 + (k4 * 4 + 1) * 128 + cg * 4);
    float4 w2 = *(const float4*)(W1 + (k4 * 4 + 2) * 128 + cg * 4);
    float4 w3 = *(const float4*)(W1 + (k4 * 4 + 3) * 128 + cg * 4);
#pragma unroll
    for (int r = 0; r < 4; ++r) {
      float4 a = *(const float4*)(lh + (rg * 4 + r) * 128 + k4 * 4);
      acc[r][0] += a.x * w0.x + a.y * w1.x + a.z * w2.x + a.w * w3.x;
      acc[r][1] += a.x * w0.y + a.y * w1.y + a.z * w2.y + a.w * w3.y;
      acc[r][2] += a.x * w0.z + a.y * w1.z + a.z * w2.z + a.w * w3.z;
      acc[r][3] += a.x * w0.w + a.y * w1.w + a.z * w2.w + a.w * w3.w;
    }
  }

  // snapshot h values needed in epilogue (before lh is overwritten by mid)
  float4 hreg[4];
#pragma unroll
  for (int r = 0; r < 4; ++r) hreg[r] = *(const float4*)(lh + (rg * 4 + r) * 128 + cg * 4);
  __syncthreads();

  {
    float4 bb = *(const float4*)(b1 + cg * 4);
#pragma unroll
    for (int r = 0; r < 4; ++r) {
      float4 o;
      o.x = fmaxf(acc[r][0] + bb.x, 0.f);
      o.y = fmaxf(acc[r][1] + bb.y, 0.f);
      o.z = fmaxf(acc[r][2] + bb.z, 0.f);
      o.w = fmaxf(acc[r][3] + bb.w, 0.f);
      *(float4*)(lh + (rg * 4 + r) * 128 + cg * 4) = o;
      acc[r][0] = acc[r][1] = acc[r][2] = acc[r][3] = 0.f;
    }
  }
  __syncthreads();

  // ---- Phase 3: GEMM2 (out = mid@W2 + b2)
  for (int k4 = 0; k4 < 32; ++k4) {
    float4 w0 = *(const float4*)(W2 + (k4 * 4 + 0) * 128 + cg * 4);
    float4 w1 = *(const float4*)(W2 + (k4 * 4 + 1) * 128 + cg * 4);
    float4 w2 = *(const float4*)(W2 + (k4 * 4 + 2) * 128 + cg * 4);
    float4 w3 = *(const float4*)(W2 + (k4 * 4 + 3) * 128 + cg * 4);
#pragma unroll
    for (int r = 0; r < 4; ++r) {
      float4 a = *(const float4*)(lh + (rg * 4 + r) * 128 + k4 * 4);
      acc[r][0] += a.x * w0.x + a.y * w1.x + a.z * w2.x + a.w * w3.x;
      acc[r][1] += a.x * w0.y + a.y * w1.y + a.z * w2.y + a.w * w3.y;
      acc[r][2] += a.x * w0.z + a.y * w1.z + a.z * w2.z + a.w * w3.z;
      acc[r][3] += a.x * w0.w + a.y * w1.w + a.z * w2.w + a.w * w3.w;
    }
  }

  // ---- Epilogue: +b2 (+h) -> relu -> +xin; write fp32 state AND bf16 shadow.
  float4 b2v = *(const float4*)(b2 + cg * 4);
  float4* xo4 = (float4*)xout;
  ushort4* xho4 = (ushort4*)xh_out;
#pragma unroll
  for (int r = 0; r < 4; ++r) {
    int row = row0 + rg * 4 + r;
    if (row < n) {
      float ox = acc[r][0] + b2v.x;
      float oy = acc[r][1] + b2v.y;
      float oz = acc[r][2] + b2v.z;
      float ow = acc[r][3] + b2v.w;
      if (addH) {
        ox += hreg[r].x; oy += hreg[r].y; oz += hreg[r].z; ow += hreg[r].w;
      }
      ox = fmaxf(ox, 0.f); oy = fmaxf(oy, 0.f); oz = fmaxf(oz, 0.f); ow = fmaxf(ow, 0.f);
      float4 xv = x4[row * 32 + cg];
      float4 o;
      o.x = ox + xv.x; o.y = oy + xv.y; o.z = oz + xv.z; o.w = ow + xv.w;
      xo4[row * 32 + cg] = o;
      ushort4 ob;
      ob.x = f2bf(o.x); ob.y = f2bf(o.y); ob.z = f2bf(o.z); ob.w = f2bf(o.w);
      xho4[row * 32 + cg] = ob;
    }
  }
}

// ---------------- pooling (batch is sorted) ----------------

__global__ __launch_bounds__(128) void pool_kernel(const float* __restrict__ x,
                                                   const int* __restrict__ batch,
                                                   float* __restrict__ pool,
                                                   int* __restrict__ gcnt, int n) {
  const int CH = 512;
  int c = threadIdx.x;
  int n0 = blockIdx.x * CH;
  if (n0 >= n) return;
  int n1 = n0 + CH; if (n1 > n) n1 = n;
  float acc = 0.f;
  int g = batch[n0];
  int cl = 0;
  for (int i = n0; i < n1; ++i) {
    int gi = batch[i];
    if (gi != g) {
      atomicAdd(&pool[g * 128 + c], acc);
      if (c == 0) atomicAdd(&gcnt[g], cl);
      acc = 0.f; cl = 0; g = gi;
    }
    acc += x[i * 128 + c];
    cl++;
  }
  atomicAdd(&pool[g * 128 + c], acc);
  if (c == 0) atomicAdd(&gcnt[g], cl);
}

// ---------------- classifier: one block per graph ----------------

__global__ __launch_bounds__(128) void classifier_kernel(const float* __restrict__ pool,
                                                         const int* __restrict__ gcnt,
                                                         const float* __restrict__ Wc1,
                                                         const float* __restrict__ bc1,
                                                         const float* __restrict__ Wc2,
                                                         const float* __restrict__ bc2,
                                                         float* __restrict__ out) {
  __shared__ float prow[128];
  __shared__ float hid[128];
  int g = blockIdx.x;
  int c = threadIdx.x;
  float cf = (float)gcnt[g];
  if (cf < 1.f) cf = 1.f;
  prow[c] = pool[g * 128 + c] / cf;
  __syncthreads();
  float a = bc1[c];
  for (int k = 0; k < 128; ++k) a += prow[k] * Wc1[k * 128 + c];
  hid[c] = fmaxf(a, 0.f);
  __syncthreads();
  if (c < 2) {
    float a2 = bc2[c];
    for (int k = 0; k < 128; ++k) a2 += hid[k] * Wc2[k * 2 + c];
    out[g * 2 + c] = a2;
  }
}

// ---------------- launch ----------------

extern "C" void kernel_launch(void* const* d_in, const int* in_sizes, int n_in,
                              void* d_out, int out_size, void* d_ws, size_t ws_size,
                              hipStream_t stream) {
  const float* x_in = (const float*)d_in[0];
  const int* edge_index = (const int*)d_in[1];
  const int* batch = (const int*)d_in[2];
  const float* eps = (const float*)d_in[3];
  const float* W1 = (const float*)d_in[4];
  const float* b1 = (const float*)d_in[5];
  const float* W2 = (const float*)d_in[6];
  const float* b2 = (const float*)d_in[7];
  const float* Wc1 = (const float*)d_in[8];
  const float* bc1 = (const float*)d_in[9];
  const float* Wc2 = (const float*)d_in[10];
  const float* bc2 = (const float*)d_in[11];
  float* out = (float*)d_out;

  const int N = N_NODES, E = N_EDGES;
  const int* src = edge_index;
  const int* dst = edge_index + E;

  // workspace layout: one fp32 state + two bf16 shadows (same footprint as 2x fp32)
  float* xa = (float*)d_ws;                        // N*128 floats (fp32 state, in-place)
  ushort_t* xha = (ushort_t*)(xa + (size_t)N * 128);   // N*128 bf16
  ushort_t* xhb = xha + (size_t)N * 128;               // N*128 bf16
  int* deg = (int*)(xhb + (size_t)N * 128);        // N
  int* rs = deg + N;                               // N+1
  int* cur = rs + (N + 1);                         // N
  int* csr = cur + N;                              // E
  float* pool = (float*)(csr + E);                 // 64*128
  int* gcnt = (int*)(pool + NUM_GRAPHS * 128);     // 64
  int* psum = gcnt + NUM_GRAPHS;                   // SCAN_BLOCKS
  int* poff = psum + SCAN_BLOCKS;                  // SCAN_BLOCKS

  hipMemsetAsync(deg, 0, N * sizeof(int), stream);

  // CSR build
  count_deg_kernel<<<(E + 255) / 256, 256, 0, stream>>>(dst, deg, E);
  block_sum_kernel<<<SCAN_BLOCKS, 256, 0, stream>>>(deg, psum, N);
  scan_partials_kernel<<<1, 512, 0, stream>>>(psum, poff, SCAN_BLOCKS);
  write_rs_kernel<<<SCAN_BLOCKS, 256, 0, stream>>>(deg, poff, rs, cur, N);
  fill_csr_kernel<<<(E + 255) / 256, 256, 0, stream>>>(src, dst, cur, csr, E);

  // bf16 shadow of the input
  cast_bf16_kernel<<<(N * 32 + 255) / 256, 256, 0, stream>>>(x_in, xha, N * 32);

  // layers: fp32 state in-place in xa (layer 0 reads x_in); bf16 shadow ping-pongs
  const int NB = (N + ROWS - 1) / ROWS;
  for (int i = 0; i < NUM_LAYERS; ++i) {
    const float* xi = (i == 0) ? x_in : xa;
    const ushort_t* gin = (i % 2 == 0) ? xha : xhb;
    ushort_t* gout = (i % 2 == 0) ? xhb : xha;
    layer_kernel<<<NB, 256, 0, stream>>>(xi, xa, gin, gout, rs, csr, eps, i,
                                         W1 + (size_t)i * 128 * 128, b1 + (size_t)i * 128,
                                         W2 + (size_t)i * 128 * 128, b2 + (size_t)i * 128,
                                         N, i > 0 ? 1 : 0);
  }

  // pooling + classifier
  hipMemsetAsync(pool, 0, NUM_GRAPHS * 128 * sizeof(float), stream);
  hipMemsetAsync(gcnt, 0, NUM_GRAPHS * sizeof(int), stream);
  pool_kernel<<<(N + 511) / 512, 128, 0, stream>>>(xa, batch, pool, gcnt, N);
  classifier_kernel<<<NUM_GRAPHS, 128, 0, stream>>>(pool, gcnt, Wc1, bc1, Wc2, bc2, out);
}